// Round 5
// baseline (1250.078 us; speedup 1.0000x reference)
//
#include <hip/hip_runtime.h>
#include <hip/hip_bf16.h>
#include <math.h>

#define NT 8192        // tokens (B*S)
#define HD 2048        // hidden
#define ID 4096        // intermediate
#define NE 8           // experts
#define MAXSLOT 18432  // worst case: 16384 + 8*255 pad, rounded to 256 -> 72 blocks
#define MAXRB 72       // MAXSLOT/256

typedef __bf16 bf16x8 __attribute__((ext_vector_type(8)));
typedef float f32x4 __attribute__((ext_vector_type(4)));

__device__ __forceinline__ float bf2f(unsigned short u){
  union{unsigned u; float f;} v; v.u = ((unsigned)u) << 16; return v.f;
}

__device__ __forceinline__ void gload_lds16(const void* g, void* l){
  __builtin_amdgcn_global_load_lds((const __attribute__((address_space(1))) void*)g,
                                   (__attribute__((address_space(3))) void*)l, 16, 0, 0);
}

// ---------- fp32 -> bf16 convert (vectorized, grid-stride) ----------
__global__ __launch_bounds__(256) void cvt_kernel(const float* __restrict__ in,
                                                  __hip_bfloat16* __restrict__ outp, int n4){
  int i = blockIdx.x * blockDim.x + threadIdx.x;
  int stride = gridDim.x * blockDim.x;
  for (; i < n4; i += stride){
    float4 v = reinterpret_cast<const float4*>(in)[i];
    union{ushort4 u; __hip_bfloat16 h[4];} o;
    o.h[0] = __float2bfloat16(v.x); o.h[1] = __float2bfloat16(v.y);
    o.h[2] = __float2bfloat16(v.z); o.h[3] = __float2bfloat16(v.w);
    reinterpret_cast<ushort4*>(outp)[i] = o.u;
  }
}

// ---------- gather tokens into slot-contiguous bf16 rows ----------
__global__ __launch_bounds__(256) void gather_cvt_kernel(
    const float* __restrict__ x, const int* __restrict__ slotTok,
    __hip_bfloat16* __restrict__ xg)
{
  const int slot = blockIdx.x;
  const int c = threadIdx.x * 8;
  const int pr = slotTok[slot];
  ushort4* dst = reinterpret_cast<ushort4*>(xg + (long)slot * HD + c);
  if (pr < 0){
    ushort4 z = {0,0,0,0};
    dst[0] = z; dst[1] = z;
    return;
  }
  const float* src = x + (long)(pr >> 1) * HD + c;
  float4 v0 = reinterpret_cast<const float4*>(src)[0];
  float4 v1 = reinterpret_cast<const float4*>(src)[1];
  union{ushort4 u; __hip_bfloat16 h[4];} a, b;
  a.h[0]=__float2bfloat16(v0.x); a.h[1]=__float2bfloat16(v0.y);
  a.h[2]=__float2bfloat16(v0.z); a.h[3]=__float2bfloat16(v0.w);
  b.h[0]=__float2bfloat16(v1.x); b.h[1]=__float2bfloat16(v1.y);
  b.h[2]=__float2bfloat16(v1.z); b.h[3]=__float2bfloat16(v1.w);
  dst[0] = a.u; dst[1] = b.u;
}

// ---------- router: fp64 logits, top-2, softmax weights ----------
__global__ __launch_bounds__(256) void router_kernel(
    const float* __restrict__ x, const float* __restrict__ gw,
    float* __restrict__ logits_out, int* __restrict__ tokExp,
    float* __restrict__ tokW, int* __restrict__ cnt)
{
  int wave = (blockIdx.x * blockDim.x + threadIdx.x) >> 6;
  int lane = threadIdx.x & 63;
  if (wave >= NT) return;
  const float* xr = x + (long)wave * HD;
  double acc[NE];
  #pragma unroll
  for (int e = 0; e < NE; e++) acc[e] = 0.0;
  for (int k = lane; k < HD; k += 64){
    double xv = (double)xr[k];
    #pragma unroll
    for (int e = 0; e < NE; e++) acc[e] += xv * (double)gw[e * HD + k];
  }
  #pragma unroll
  for (int e = 0; e < NE; e++){
    #pragma unroll
    for (int off = 32; off; off >>= 1) acc[e] += __shfl_down(acc[e], off, 64);
  }
  if (lane == 0){
    int e0 = 0; double v0 = acc[0];
    for (int e = 1; e < NE; e++) if (acc[e] > v0){ v0 = acc[e]; e0 = e; }
    int e1 = -1; double v1 = -1e300;
    for (int e = 0; e < NE; e++) if (e != e0 && acc[e] > v1){ v1 = acc[e]; e1 = e; }
    double ex = exp(v1 - v0);
    double s = 1.0 + ex;
    for (int e = 0; e < NE; e++) logits_out[wave * NE + e] = (float)acc[e];
    tokExp[wave * 2]     = e0; tokExp[wave * 2 + 1] = e1;
    tokW[wave * 2]       = (float)(1.0 / s);
    tokW[wave * 2 + 1]   = (float)(ex / s);
    atomicAdd(&cnt[e0], 1); atomicAdd(&cnt[e1], 1);
  }
}

// ---------- padded (256) exclusive prefix over expert counts ----------
__global__ void offsets_kernel(const int* __restrict__ cnt, int* __restrict__ padOff){
  if (threadIdx.x == 0 && blockIdx.x == 0){
    int o = 0;
    for (int e = 0; e < NE; e++){ padOff[e] = o; o += ((cnt[e] + 255) >> 8) << 8; }
    padOff[NE] = o;
  }
}

// ---------- scatter: slotTok[slot] = token*2 + which (pair id), -1 for pads ----------
__global__ __launch_bounds__(256) void scatter_kernel(
    const int* __restrict__ tokExp, const int* __restrict__ padOff, int* cursor,
    int* __restrict__ slotTok)
{
  int t = blockIdx.x * blockDim.x + threadIdx.x;
  if (t >= NT) return;
  #pragma unroll
  for (int s = 0; s < 2; s++){
    int e = tokExp[t * 2 + s];
    int pos = atomicAdd(&cursor[e], 1);
    slotTok[padOff[e] + pos] = t * 2 + s;
  }
}

// ================= 256x256 8-phase grouped GEMM =================
// AGATHER: 0 = A row is the slot row directly (contiguous); 1 = slotTok>>1 (token);
//          2 = slotTok (pair id).
// WSC: 0 = write Yout[slot row] unconditionally; 1 = write Yout[slotTok row], skip pads.
// EPI: 0 = gelu(acc+bias); 1 = acc+bias.
// Schedule/LDS/swizzle identical to round 4 (verified: 0 bank conflicts).

#define LDA(buf,kk,m) (*reinterpret_cast<const bf16x8*>(&lds[((buf)*2+(kk))*8192 + (wr*8+(m))*512 + laneF]))
#define LDB(buf,kk,n) (*reinterpret_cast<const bf16x8*>(&lds[32768 + ((buf)*2+(kk))*8192 + (wc*4+(n))*512 + laneF]))
#define STAGE_A(buf,kk,koff) do{ \
    __hip_bfloat16* d_ = &lds[((buf)*2+(kk))*8192 + w*1024]; \
    gload_lds16(aS0 + (koff), d_); \
    gload_lds16(aS1 + (koff), d_ + 512); \
  }while(0)
#define STAGE_B(buf,kk,koff) do{ \
    __hip_bfloat16* d_ = &lds[32768 + ((buf)*2+(kk))*8192 + w*1024]; \
    gload_lds16(bS0 + (koff), d_); \
    gload_lds16(bS1 + (koff), d_ + 512); \
  }while(0)
#define MFMA16(M0,A0_,A1_,A2_,A3_) do{ \
    acc[(M0)+0][0] = __builtin_amdgcn_mfma_f32_16x16x32_bf16(A0_, bv0, acc[(M0)+0][0],0,0,0); \
    acc[(M0)+1][0] = __builtin_amdgcn_mfma_f32_16x16x32_bf16(A1_, bv0, acc[(M0)+1][0],0,0,0); \
    acc[(M0)+2][0] = __builtin_amdgcn_mfma_f32_16x16x32_bf16(A2_, bv0, acc[(M0)+2][0],0,0,0); \
    acc[(M0)+3][0] = __builtin_amdgcn_mfma_f32_16x16x32_bf16(A3_, bv0, acc[(M0)+3][0],0,0,0); \
    acc[(M0)+0][1] = __builtin_amdgcn_mfma_f32_16x16x32_bf16(A0_, bv1, acc[(M0)+0][1],0,0,0); \
    acc[(M0)+1][1] = __builtin_amdgcn_mfma_f32_16x16x32_bf16(A1_, bv1, acc[(M0)+1][1],0,0,0); \
    acc[(M0)+2][1] = __builtin_amdgcn_mfma_f32_16x16x32_bf16(A2_, bv1, acc[(M0)+2][1],0,0,0); \
    acc[(M0)+3][1] = __builtin_amdgcn_mfma_f32_16x16x32_bf16(A3_, bv1, acc[(M0)+3][1],0,0,0); \
    acc[(M0)+0][2] = __builtin_amdgcn_mfma_f32_16x16x32_bf16(A0_, bv2, acc[(M0)+0][2],0,0,0); \
    acc[(M0)+1][2] = __builtin_amdgcn_mfma_f32_16x16x32_bf16(A1_, bv2, acc[(M0)+1][2],0,0,0); \
    acc[(M0)+2][2] = __builtin_amdgcn_mfma_f32_16x16x32_bf16(A2_, bv2, acc[(M0)+2][2],0,0,0); \
    acc[(M0)+3][2] = __builtin_amdgcn_mfma_f32_16x16x32_bf16(A3_, bv2, acc[(M0)+3][2],0,0,0); \
    acc[(M0)+0][3] = __builtin_amdgcn_mfma_f32_16x16x32_bf16(A0_, bv3, acc[(M0)+0][3],0,0,0); \
    acc[(M0)+1][3] = __builtin_amdgcn_mfma_f32_16x16x32_bf16(A1_, bv3, acc[(M0)+1][3],0,0,0); \
    acc[(M0)+2][3] = __builtin_amdgcn_mfma_f32_16x16x32_bf16(A2_, bv3, acc[(M0)+2][3],0,0,0); \
    acc[(M0)+3][3] = __builtin_amdgcn_mfma_f32_16x16x32_bf16(A3_, bv3, acc[(M0)+3][3],0,0,0); \
  }while(0)

template<int AGATHER, int WSC, int EPI, int ND, int KD>
__global__ __launch_bounds__(512, 2) void moe_gemm8(
    const __hip_bfloat16* __restrict__ A,
    const __hip_bfloat16* __restrict__ W,
    const float* __restrict__ bias,
    const int* __restrict__ slotTok,
    const int* __restrict__ padOff,
    __hip_bfloat16* __restrict__ Yout)
{
  __shared__ __align__(16) __hip_bfloat16 lds[65536];  // 128 KiB
  const int rb = blockIdx.y;
  if (rb * 256 >= padOff[NE]) return;
  const int cb = blockIdx.x;
  int e = 0;
  #pragma unroll
  for (int i = 1; i < NE; i++) if (rb * 256 >= padOff[i]) e = i;

  const int tid  = threadIdx.x;
  const int lane = tid & 63;
  const int w    = tid >> 6;   // 0..7
  const int wr   = w >> 2;     // 0..1 (M half)
  const int wc   = w & 3;      // 0..3 (N quarter)

  // ---- staging addresses (wave w stages subtiles 2w,2w+1 = rows 32w..32w+31)
  const int r16s = lane >> 2;
  const int cgs  = (lane & 3) ^ ((r16s >> 1) & 3);   // inverse swizzle on global k-chunk
  const int r0 = rb * 256 + 32 * w + r16s;
  long ga0, ga1;
  if (AGATHER == 0){
    ga0 = r0; ga1 = r0 + 16;
  } else {
    int p0 = slotTok[r0], p1 = slotTok[r0 + 16];
    ga0 = p0 < 0 ? 0 : (AGATHER == 1 ? (p0 >> 1) : p0);
    ga1 = p1 < 0 ? 0 : (AGATHER == 1 ? (p1 >> 1) : p1);
  }
  const __hip_bfloat16* aS0 = A + ga0 * (long)KD + cgs * 8;
  const __hip_bfloat16* aS1 = A + ga1 * (long)KD + cgs * 8;
  const long rowB = (long)cb * 256 + 32 * w + r16s;
  const __hip_bfloat16* bS0 = W + (long)e * ND * KD + rowB * KD + cgs * 8;
  const __hip_bfloat16* bS1 = bS0 + 16 * (long)KD;

  // ---- fragment read lane offset (swizzled)
  const int r16f = lane & 15;
  const int chf  = lane >> 4;
  const int laneF = r16f * 32 + (chf ^ ((r16f >> 1) & 3)) * 8;

  f32x4 acc[8][4] = {};
  bf16x8 bv0, bv1, bv2, bv3;

  constexpr int NTILES = KD / 64;

  // ---- prologue: stage tiles 0 and 1 fully
  STAGE_A(0,0,0);   STAGE_B(0,0,0);
  STAGE_A(0,1,32);  STAGE_B(0,1,32);
  STAGE_A(1,0,64);  STAGE_B(1,0,64);
  STAGE_A(1,1,96);  STAGE_B(1,1,96);
  asm volatile("s_waitcnt vmcnt(8)" ::: "memory");   // tile 0 fully resident
  __builtin_amdgcn_s_barrier();

  for (int t = 0; t < NTILES; ++t){
    const int b = t & 1;
    const bool s01 = (t >= 1) && (t + 1 < NTILES);
    const bool s23 = (t + 2 < NTILES);
    const long ko01 = (long)(t + 1) * 64 + 32;
    const long ko23 = (long)(t + 2) * 64;
    // ---- phase 0: (b,kk0) m0-3
    {
      bf16x8 a0 = LDA(b,0,0), a1 = LDA(b,0,1), a2 = LDA(b,0,2), a3 = LDA(b,0,3);
      bv0 = LDB(b,0,0); bv1 = LDB(b,0,1); bv2 = LDB(b,0,2); bv3 = LDB(b,0,3);
      if (s01){ STAGE_A(b^1,1,ko01); }
      __builtin_amdgcn_s_barrier();
      asm volatile("s_waitcnt lgkmcnt(0)" ::: "memory");
      __builtin_amdgcn_s_setprio(1);
      MFMA16(0, a0, a1, a2, a3);
      __builtin_amdgcn_s_setprio(0);
      __builtin_amdgcn_s_barrier();
    }
    // ---- phase 1: (b,kk0) m4-7
    {
      bf16x8 a0 = LDA(b,0,4), a1 = LDA(b,0,5), a2 = LDA(b,0,6), a3 = LDA(b,0,7);
      if (s01){ STAGE_B(b^1,1,ko01); }
      __builtin_amdgcn_s_barrier();
      asm volatile("s_waitcnt lgkmcnt(0)" ::: "memory");
      __builtin_amdgcn_s_setprio(1);
      MFMA16(4, a0, a1, a2, a3);
      __builtin_amdgcn_s_setprio(0);
      __builtin_amdgcn_s_barrier();
    }
    // ---- phase 2: (b,kk1) m0-3
    {
      bf16x8 a0 = LDA(b,1,0), a1 = LDA(b,1,1), a2 = LDA(b,1,2), a3 = LDA(b,1,3);
      bv0 = LDB(b,1,0); bv1 = LDB(b,1,1); bv2 = LDB(b,1,2); bv3 = LDB(b,1,3);
      if (s23){ STAGE_A(b,0,ko23); }
      __builtin_amdgcn_s_barrier();
      asm volatile("s_waitcnt lgkmcnt(0)" ::: "memory");
      __builtin_amdgcn_s_setprio(1);
      MFMA16(0, a0, a1, a2, a3);
      __builtin_amdgcn_s_setprio(0);
      __builtin_amdgcn_s_barrier();
    }
    // ---- phase 3: (b,kk1) m4-7; counted vmcnt BEFORE boundary barrier
    {
      bf16x8 a0 = LDA(b,1,4), a1 = LDA(b,1,5), a2 = LDA(b,1,6), a3 = LDA(b,1,7);
      if (s23){ STAGE_B(b,0,ko23); }
      __builtin_amdgcn_s_barrier();
      asm volatile("s_waitcnt lgkmcnt(0)" ::: "memory");
      __builtin_amdgcn_s_setprio(1);
      MFMA16(4, a0, a1, a2, a3);
      __builtin_amdgcn_s_setprio(0);
      if (s23) asm volatile("s_waitcnt vmcnt(4)" ::: "memory");
      else     asm volatile("s_waitcnt vmcnt(0)" ::: "memory");
      __builtin_amdgcn_s_barrier();
    }
  }

  // ---- epilogue: C layout col=lane&15, row=(lane>>4)*4+reg
  const int colBase = cb * 256 + wc * 64 + (lane & 15);
  const int rowQ = (lane >> 4) * 4;
  float bb[4];
  #pragma unroll
  for (int n = 0; n < 4; n++) bb[n] = bias[(long)e * ND + colBase + n * 16];
  #pragma unroll
  for (int m = 0; m < 8; m++){
    const int grow = rb * 256 + wr * 128 + m * 16 + rowQ;
    #pragma unroll
    for (int r = 0; r < 4; r++){
      long orow;
      bool doW;
      if (WSC == 0){ orow = grow + r; doW = true; }
      else { int pr = slotTok[grow + r]; orow = pr; doW = (pr >= 0); }
      if (doW){
        #pragma unroll
        for (int n = 0; n < 4; n++){
          float v = acc[m][n][r] + bb[n];
          if (EPI == 0){
            v = 0.5f * v * (1.0f + erff(v * 0.70710678118654752f));  // exact gelu
          }
          Yout[orow * ND + colBase + n * 16] = __float2bfloat16(v);
        }
      }
    }
  }
}

// ---------- combine (in-place over d_out): out[t] = w0*y[2t] + w1*y[2t+1] ----------
// y pair rows live in d_out's bytes (bf16); block t reads its 8 KB range, barrier, writes fp32.
__global__ __launch_bounds__(256) void combine_kernel(
    const __hip_bfloat16* __restrict__ yb, const float* __restrict__ tokW,
    float* __restrict__ outp)
{
  const int t  = blockIdx.x;
  const int c0 = threadIdx.x * 8;
  const float w0 = tokW[t * 2], w1 = tokW[t * 2 + 1];
  const ushort4* p0 = reinterpret_cast<const ushort4*>(yb + (long)(2 * t) * HD + c0);
  const ushort4* p1 = reinterpret_cast<const ushort4*>(yb + (long)(2 * t + 1) * HD + c0);
  float4 o[2];
  #pragma unroll
  for (int h = 0; h < 2; h++){
    ushort4 a = p0[h], b = p1[h];
    o[h].x = w0 * bf2f(a.x) + w1 * bf2f(b.x);
    o[h].y = w0 * bf2f(a.y) + w1 * bf2f(b.y);
    o[h].z = w0 * bf2f(a.z) + w1 * bf2f(b.z);
    o[h].w = w0 * bf2f(a.w) + w1 * bf2f(b.w);
  }
  __syncthreads();   // all reads of this block's byte-range done before in-place overwrite
  float4* po = reinterpret_cast<float4*>(outp + (long)t * HD + c0);
  po[0] = o[0]; po[1] = o[1];
}

extern "C" void kernel_launch(void* const* d_in, const int* in_sizes, int n_in,
                              void* d_out, int out_size, void* d_ws, size_t ws_size,
                              hipStream_t stream)
{
  (void)in_sizes; (void)n_in; (void)out_size;
  const float* x     = (const float*)d_in[0];
  const float* gw    = (const float*)d_in[1];
  const float* wfc   = (const float*)d_in[2];
  const float* bfc   = (const float*)d_in[3];
  const float* wproj = (const float*)d_in[4];
  const float* bproj = (const float*)d_in[5];
  float* outp   = (float*)d_out;
  float* logits = outp + (size_t)NT * HD;
  __hip_bfloat16* yb = (__hip_bfloat16*)d_out;   // proj writes pair rows here; combine in-place

  char* ws = (char*)d_ws;
  size_t off = 0;
  auto alloc = [&](size_t b){ void* p = ws + off; off += (b + 255) & ~(size_t)255; return p; };

  // ---- slot-contiguous layout (preferred)
  const size_t XG_B  = (size_t)MAXSLOT * HD * 2;   // 75.5 MB
  const size_t HBS_B = (size_t)MAXSLOT * ID * 2;   // 151.0 MB
  const size_t WB_B  = (size_t)NE * ID * HD * 2;   // 134.2 MB
  const size_t MISC_B = (size_t)MAXSLOT*4 + NT*2*4 + NT*2*4 + 4096;
  const bool slotPath = (XG_B + HBS_B + WB_B + MISC_B + 4096) <= ws_size;

  __hip_bfloat16 *xg, *hb, *wB;
  if (slotPath){
    xg = (__hip_bfloat16*)alloc(XG_B);
    hb = (__hip_bfloat16*)alloc(HBS_B);
    wB = (__hip_bfloat16*)alloc(WB_B);
  } else {
    xg = (__hip_bfloat16*)alloc((size_t)NT * HD * 2);        // token-order xb
    hb = (__hip_bfloat16*)alloc((size_t)NT * 2 * ID * 2);    // pair-space hb
    wB = (__hip_bfloat16*)alloc(WB_B);
  }
  int*   slotTok = (int*)alloc(MAXSLOT * 4);
  int*   tokExp  = (int*)alloc(NT * 2 * 4);
  float* tokW    = (float*)alloc(NT * 2 * 4);
  int*   meta    = (int*)alloc(256);
  int* cnt = meta; int* cursor = meta + 8; int* padOff = meta + 16;

  hipMemsetAsync(meta, 0, 256, stream);
  hipMemsetAsync(slotTok, 0xFF, MAXSLOT * 4, stream);

  router_kernel<<<NT / 4, 256, 0, stream>>>(x, gw, logits, tokExp, tokW, cnt);
  offsets_kernel<<<1, 64, 0, stream>>>(cnt, padOff);
  scatter_kernel<<<NT / 256, 256, 0, stream>>>(tokExp, padOff, cursor, slotTok);

  if (slotPath){
    gather_cvt_kernel<<<MAXSLOT, 256, 0, stream>>>(x, slotTok, xg);
    cvt_kernel<<<2048, 256, 0, stream>>>(wfc, wB, NE * ID * HD / 4);
    moe_gemm8<0, 0, 0, ID, HD><<<dim3(ID / 256, MAXRB), 512, 0, stream>>>(xg, wB, bfc, slotTok, padOff, hb);
    cvt_kernel<<<2048, 256, 0, stream>>>(wproj, wB, NE * HD * ID / 4);
    moe_gemm8<0, 1, 1, HD, ID><<<dim3(HD / 256, MAXRB), 512, 0, stream>>>(hb, wB, bproj, slotTok, padOff, yb);
  } else {
    cvt_kernel<<<2048, 256, 0, stream>>>(x, xg, NT * HD / 4);
    cvt_kernel<<<2048, 256, 0, stream>>>(wfc, wB, NE * ID * HD / 4);
    moe_gemm8<1, 1, 0, ID, HD><<<dim3(ID / 256, MAXRB), 512, 0, stream>>>(xg, wB, bfc, slotTok, padOff, hb);
    cvt_kernel<<<2048, 256, 0, stream>>>(wproj, wB, NE * HD * ID / 4);
    moe_gemm8<2, 1, 1, HD, ID><<<dim3(HD / 256, MAXRB), 512, 0, stream>>>(hb, wB, bproj, slotTok, padOff, yb);
  }

  combine_kernel<<<NT, 256, 0, stream>>>(yb, tokW, outp);
}

// Round 6
// 1249.050 us; speedup vs baseline: 1.0008x; 1.0008x over previous
//
#include <hip/hip_runtime.h>
#include <hip/hip_bf16.h>
#include <math.h>

#define NT 8192        // tokens (B*S)
#define HD 2048        // hidden
#define ID 4096        // intermediate
#define NE 8           // experts
#define MAXSLOT 18432  // worst case: 16384 + 8*255 pad, rounded to 256 -> 72 blocks
#define MAXRB 72       // MAXSLOT/256

typedef __bf16 bf16x8 __attribute__((ext_vector_type(8)));
typedef float f32x4 __attribute__((ext_vector_type(4)));

__device__ __forceinline__ float bf2f(unsigned short u){
  union{unsigned u; float f;} v; v.u = ((unsigned)u) << 16; return v.f;
}

__device__ __forceinline__ void gload_lds16(const void* g, void* l){
  __builtin_amdgcn_global_load_lds((const __attribute__((address_space(1))) void*)g,
                                   (__attribute__((address_space(3))) void*)l, 16, 0, 0);
}

// ---------- fp32 -> bf16 convert (vectorized, grid-stride) ----------
__global__ __launch_bounds__(256) void cvt_kernel(const float* __restrict__ in,
                                                  __hip_bfloat16* __restrict__ outp, int n4){
  int i = blockIdx.x * blockDim.x + threadIdx.x;
  int stride = gridDim.x * blockDim.x;
  for (; i < n4; i += stride){
    float4 v = reinterpret_cast<const float4*>(in)[i];
    union{ushort4 u; __hip_bfloat16 h[4];} o;
    o.h[0] = __float2bfloat16(v.x); o.h[1] = __float2bfloat16(v.y);
    o.h[2] = __float2bfloat16(v.z); o.h[3] = __float2bfloat16(v.w);
    reinterpret_cast<ushort4*>(outp)[i] = o.u;
  }
}

// ---------- gather tokens into slot-contiguous bf16 rows ----------
__global__ __launch_bounds__(256) void gather_cvt_kernel(
    const float* __restrict__ x, const int* __restrict__ slotTok,
    __hip_bfloat16* __restrict__ xg)
{
  const int slot = blockIdx.x;
  const int c = threadIdx.x * 8;
  const int pr = slotTok[slot];
  ushort4* dst = reinterpret_cast<ushort4*>(xg + (long)slot * HD + c);
  if (pr < 0){
    ushort4 z = {0,0,0,0};
    dst[0] = z; dst[1] = z;
    return;
  }
  const float* src = x + (long)(pr >> 1) * HD + c;
  float4 v0 = reinterpret_cast<const float4*>(src)[0];
  float4 v1 = reinterpret_cast<const float4*>(src)[1];
  union{ushort4 u; __hip_bfloat16 h[4];} a, b;
  a.h[0]=__float2bfloat16(v0.x); a.h[1]=__float2bfloat16(v0.y);
  a.h[2]=__float2bfloat16(v0.z); a.h[3]=__float2bfloat16(v0.w);
  b.h[0]=__float2bfloat16(v1.x); b.h[1]=__float2bfloat16(v1.y);
  b.h[2]=__float2bfloat16(v1.z); b.h[3]=__float2bfloat16(v1.w);
  dst[0] = a.u; dst[1] = b.u;
}

// ---------- router: fp64 logits, top-2, softmax weights ----------
__global__ __launch_bounds__(256) void router_kernel(
    const float* __restrict__ x, const float* __restrict__ gw,
    float* __restrict__ logits_out, int* __restrict__ tokExp,
    float* __restrict__ tokW, int* __restrict__ cnt)
{
  int wave = (blockIdx.x * blockDim.x + threadIdx.x) >> 6;
  int lane = threadIdx.x & 63;
  if (wave >= NT) return;
  const float* xr = x + (long)wave * HD;
  double acc[NE];
  #pragma unroll
  for (int e = 0; e < NE; e++) acc[e] = 0.0;
  for (int k = lane; k < HD; k += 64){
    double xv = (double)xr[k];
    #pragma unroll
    for (int e = 0; e < NE; e++) acc[e] += xv * (double)gw[e * HD + k];
  }
  #pragma unroll
  for (int e = 0; e < NE; e++){
    #pragma unroll
    for (int off = 32; off; off >>= 1) acc[e] += __shfl_down(acc[e], off, 64);
  }
  if (lane == 0){
    int e0 = 0; double v0 = acc[0];
    for (int e = 1; e < NE; e++) if (acc[e] > v0){ v0 = acc[e]; e0 = e; }
    int e1 = -1; double v1 = -1e300;
    for (int e = 0; e < NE; e++) if (e != e0 && acc[e] > v1){ v1 = acc[e]; e1 = e; }
    double ex = exp(v1 - v0);
    double s = 1.0 + ex;
    for (int e = 0; e < NE; e++) logits_out[wave * NE + e] = (float)acc[e];
    tokExp[wave * 2]     = e0; tokExp[wave * 2 + 1] = e1;
    tokW[wave * 2]       = (float)(1.0 / s);
    tokW[wave * 2 + 1]   = (float)(ex / s);
    atomicAdd(&cnt[e0], 1); atomicAdd(&cnt[e1], 1);
  }
}

// ---------- padded (256) exclusive prefix over expert counts ----------
__global__ void offsets_kernel(const int* __restrict__ cnt, int* __restrict__ padOff){
  if (threadIdx.x == 0 && blockIdx.x == 0){
    int o = 0;
    for (int e = 0; e < NE; e++){ padOff[e] = o; o += ((cnt[e] + 255) >> 8) << 8; }
    padOff[NE] = o;
  }
}

// ---------- scatter: slotTok[slot] = token*2 + which (pair id), -1 for pads ----------
__global__ __launch_bounds__(256) void scatter_kernel(
    const int* __restrict__ tokExp, const int* __restrict__ padOff, int* cursor,
    int* __restrict__ slotTok)
{
  int t = blockIdx.x * blockDim.x + threadIdx.x;
  if (t >= NT) return;
  #pragma unroll
  for (int s = 0; s < 2; s++){
    int e = tokExp[t * 2 + s];
    int pos = atomicAdd(&cursor[e], 1);
    slotTok[padOff[e] + pos] = t * 2 + s;
  }
}

// ================= 256x256 8-phase grouped GEMM, XCD-supertiled =================
// Block remap: 1-D grid, xcd = bid&7, g = bid>>3, cb = xcd + 8*(g/MAXRB), rb = g%MAXRB.
// => all 32 CUs of an XCD run the SAME cb column concurrently: its 1-2 MB B panel
//    stays L2-resident (reused 32-65x); A panels shared across XCDs via L3.
// AGATHER: 0 = A row is the slot row directly; 1 = slotTok>>1 (token); 2 = slotTok (pair).
// WSC: 0 = write Yout[slot row]; 1 = write Yout[slotTok row], skip pads.
// EPI: 0 = gelu(acc+bias); 1 = acc+bias.
// Schedule/LDS/swizzle identical to round 4/5 (verified correct, 0 bank conflicts).

#define LDA(buf,kk,m) (*reinterpret_cast<const bf16x8*>(&lds[((buf)*2+(kk))*8192 + (wr*8+(m))*512 + laneF]))
#define LDB(buf,kk,n) (*reinterpret_cast<const bf16x8*>(&lds[32768 + ((buf)*2+(kk))*8192 + (wc*4+(n))*512 + laneF]))
#define STAGE_A(buf,kk,koff) do{ \
    __hip_bfloat16* d_ = &lds[((buf)*2+(kk))*8192 + w*1024]; \
    gload_lds16(aS0 + (koff), d_); \
    gload_lds16(aS1 + (koff), d_ + 512); \
  }while(0)
#define STAGE_B(buf,kk,koff) do{ \
    __hip_bfloat16* d_ = &lds[32768 + ((buf)*2+(kk))*8192 + w*1024]; \
    gload_lds16(bS0 + (koff), d_); \
    gload_lds16(bS1 + (koff), d_ + 512); \
  }while(0)
#define MFMA16(M0,A0_,A1_,A2_,A3_) do{ \
    acc[(M0)+0][0] = __builtin_amdgcn_mfma_f32_16x16x32_bf16(A0_, bv0, acc[(M0)+0][0],0,0,0); \
    acc[(M0)+1][0] = __builtin_amdgcn_mfma_f32_16x16x32_bf16(A1_, bv0, acc[(M0)+1][0],0,0,0); \
    acc[(M0)+2][0] = __builtin_amdgcn_mfma_f32_16x16x32_bf16(A2_, bv0, acc[(M0)+2][0],0,0,0); \
    acc[(M0)+3][0] = __builtin_amdgcn_mfma_f32_16x16x32_bf16(A3_, bv0, acc[(M0)+3][0],0,0,0); \
    acc[(M0)+0][1] = __builtin_amdgcn_mfma_f32_16x16x32_bf16(A0_, bv1, acc[(M0)+0][1],0,0,0); \
    acc[(M0)+1][1] = __builtin_amdgcn_mfma_f32_16x16x32_bf16(A1_, bv1, acc[(M0)+1][1],0,0,0); \
    acc[(M0)+2][1] = __builtin_amdgcn_mfma_f32_16x16x32_bf16(A2_, bv1, acc[(M0)+2][1],0,0,0); \
    acc[(M0)+3][1] = __builtin_amdgcn_mfma_f32_16x16x32_bf16(A3_, bv1, acc[(M0)+3][1],0,0,0); \
    acc[(M0)+0][2] = __builtin_amdgcn_mfma_f32_16x16x32_bf16(A0_, bv2, acc[(M0)+0][2],0,0,0); \
    acc[(M0)+1][2] = __builtin_amdgcn_mfma_f32_16x16x32_bf16(A1_, bv2, acc[(M0)+1][2],0,0,0); \
    acc[(M0)+2][2] = __builtin_amdgcn_mfma_f32_16x16x32_bf16(A2_, bv2, acc[(M0)+2][2],0,0,0); \
    acc[(M0)+3][2] = __builtin_amdgcn_mfma_f32_16x16x32_bf16(A3_, bv2, acc[(M0)+3][2],0,0,0); \
    acc[(M0)+0][3] = __builtin_amdgcn_mfma_f32_16x16x32_bf16(A0_, bv3, acc[(M0)+0][3],0,0,0); \
    acc[(M0)+1][3] = __builtin_amdgcn_mfma_f32_16x16x32_bf16(A1_, bv3, acc[(M0)+1][3],0,0,0); \
    acc[(M0)+2][3] = __builtin_amdgcn_mfma_f32_16x16x32_bf16(A2_, bv3, acc[(M0)+2][3],0,0,0); \
    acc[(M0)+3][3] = __builtin_amdgcn_mfma_f32_16x16x32_bf16(A3_, bv3, acc[(M0)+3][3],0,0,0); \
  }while(0)

template<int AGATHER, int WSC, int EPI, int ND, int KD>
__global__ __launch_bounds__(512, 2) void moe_gemm8(
    const __hip_bfloat16* __restrict__ A,
    const __hip_bfloat16* __restrict__ W,
    const float* __restrict__ bias,
    const int* __restrict__ slotTok,
    const int* __restrict__ padOff,
    __hip_bfloat16* __restrict__ Yout)
{
  __shared__ __align__(16) __hip_bfloat16 lds[65536];  // 128 KiB
  // ---- XCD supertile remap (NCB = ND/256 columns, NCB%8==0)
  const int bid = blockIdx.x;
  const int xcd = bid & 7;
  const int g   = bid >> 3;
  const int cb  = xcd + 8 * (g / MAXRB);
  const int rb  = g % MAXRB;
  if (rb * 256 >= padOff[NE]) return;
  int e = 0;
  #pragma unroll
  for (int i = 1; i < NE; i++) if (rb * 256 >= padOff[i]) e = i;

  const int tid  = threadIdx.x;
  const int lane = tid & 63;
  const int w    = tid >> 6;   // 0..7
  const int wr   = w >> 2;     // 0..1 (M half)
  const int wc   = w & 3;      // 0..3 (N quarter)

  // ---- staging addresses (wave w stages subtiles 2w,2w+1 = rows 32w..32w+31)
  const int r16s = lane >> 2;
  const int cgs  = (lane & 3) ^ ((r16s >> 1) & 3);   // inverse swizzle on global k-chunk
  const int r0 = rb * 256 + 32 * w + r16s;
  long ga0, ga1;
  if (AGATHER == 0){
    ga0 = r0; ga1 = r0 + 16;
  } else {
    int p0 = slotTok[r0], p1 = slotTok[r0 + 16];
    ga0 = p0 < 0 ? 0 : (AGATHER == 1 ? (p0 >> 1) : p0);
    ga1 = p1 < 0 ? 0 : (AGATHER == 1 ? (p1 >> 1) : p1);
  }
  const __hip_bfloat16* aS0 = A + ga0 * (long)KD + cgs * 8;
  const __hip_bfloat16* aS1 = A + ga1 * (long)KD + cgs * 8;
  const long rowB = (long)cb * 256 + 32 * w + r16s;
  const __hip_bfloat16* bS0 = W + (long)e * ND * KD + rowB * KD + cgs * 8;
  const __hip_bfloat16* bS1 = bS0 + 16 * (long)KD;

  // ---- fragment read lane offset (swizzled)
  const int r16f = lane & 15;
  const int chf  = lane >> 4;
  const int laneF = r16f * 32 + (chf ^ ((r16f >> 1) & 3)) * 8;

  f32x4 acc[8][4] = {};
  bf16x8 bv0, bv1, bv2, bv3;

  constexpr int NTILES = KD / 64;

  // ---- prologue: stage tiles 0 and 1 fully
  STAGE_A(0,0,0);   STAGE_B(0,0,0);
  STAGE_A(0,1,32);  STAGE_B(0,1,32);
  STAGE_A(1,0,64);  STAGE_B(1,0,64);
  STAGE_A(1,1,96);  STAGE_B(1,1,96);
  asm volatile("s_waitcnt vmcnt(8)" ::: "memory");   // tile 0 fully resident
  __builtin_amdgcn_s_barrier();

  for (int t = 0; t < NTILES; ++t){
    const int b = t & 1;
    const bool s01 = (t >= 1) && (t + 1 < NTILES);
    const bool s23 = (t + 2 < NTILES);
    const long ko01 = (long)(t + 1) * 64 + 32;
    const long ko23 = (long)(t + 2) * 64;
    // ---- phase 0: (b,kk0) m0-3
    {
      bf16x8 a0 = LDA(b,0,0), a1 = LDA(b,0,1), a2 = LDA(b,0,2), a3 = LDA(b,0,3);
      bv0 = LDB(b,0,0); bv1 = LDB(b,0,1); bv2 = LDB(b,0,2); bv3 = LDB(b,0,3);
      if (s01){ STAGE_A(b^1,1,ko01); }
      __builtin_amdgcn_s_barrier();
      asm volatile("s_waitcnt lgkmcnt(0)" ::: "memory");
      __builtin_amdgcn_s_setprio(1);
      MFMA16(0, a0, a1, a2, a3);
      __builtin_amdgcn_s_setprio(0);
      __builtin_amdgcn_s_barrier();
    }
    // ---- phase 1: (b,kk0) m4-7
    {
      bf16x8 a0 = LDA(b,0,4), a1 = LDA(b,0,5), a2 = LDA(b,0,6), a3 = LDA(b,0,7);
      if (s01){ STAGE_B(b^1,1,ko01); }
      __builtin_amdgcn_s_barrier();
      asm volatile("s_waitcnt lgkmcnt(0)" ::: "memory");
      __builtin_amdgcn_s_setprio(1);
      MFMA16(4, a0, a1, a2, a3);
      __builtin_amdgcn_s_setprio(0);
      __builtin_amdgcn_s_barrier();
    }
    // ---- phase 2: (b,kk1) m0-3
    {
      bf16x8 a0 = LDA(b,1,0), a1 = LDA(b,1,1), a2 = LDA(b,1,2), a3 = LDA(b,1,3);
      bv0 = LDB(b,1,0); bv1 = LDB(b,1,1); bv2 = LDB(b,1,2); bv3 = LDB(b,1,3);
      if (s23){ STAGE_A(b,0,ko23); }
      __builtin_amdgcn_s_barrier();
      asm volatile("s_waitcnt lgkmcnt(0)" ::: "memory");
      __builtin_amdgcn_s_setprio(1);
      MFMA16(0, a0, a1, a2, a3);
      __builtin_amdgcn_s_setprio(0);
      __builtin_amdgcn_s_barrier();
    }
    // ---- phase 3: (b,kk1) m4-7; counted vmcnt BEFORE boundary barrier
    {
      bf16x8 a0 = LDA(b,1,4), a1 = LDA(b,1,5), a2 = LDA(b,1,6), a3 = LDA(b,1,7);
      if (s23){ STAGE_B(b,0,ko23); }
      __builtin_amdgcn_s_barrier();
      asm volatile("s_waitcnt lgkmcnt(0)" ::: "memory");
      __builtin_amdgcn_s_setprio(1);
      MFMA16(4, a0, a1, a2, a3);
      __builtin_amdgcn_s_setprio(0);
      if (s23) asm volatile("s_waitcnt vmcnt(4)" ::: "memory");
      else     asm volatile("s_waitcnt vmcnt(0)" ::: "memory");
      __builtin_amdgcn_s_barrier();
    }
  }

  // ---- epilogue: C layout col=lane&15, row=(lane>>4)*4+reg
  const int colBase = cb * 256 + wc * 64 + (lane & 15);
  const int rowQ = (lane >> 4) * 4;
  float bb[4];
  #pragma unroll
  for (int n = 0; n < 4; n++) bb[n] = bias[(long)e * ND + colBase + n * 16];
  #pragma unroll
  for (int m = 0; m < 8; m++){
    const int grow = rb * 256 + wr * 128 + m * 16 + rowQ;
    #pragma unroll
    for (int r = 0; r < 4; r++){
      long orow;
      bool doW;
      if (WSC == 0){ orow = grow + r; doW = true; }
      else { int pr = slotTok[grow + r]; orow = pr; doW = (pr >= 0); }
      if (doW){
        #pragma unroll
        for (int n = 0; n < 4; n++){
          float v = acc[m][n][r] + bb[n];
          if (EPI == 0){
            v = 0.5f * v * (1.0f + erff(v * 0.70710678118654752f));  // exact gelu
          }
          Yout[orow * ND + colBase + n * 16] = __float2bfloat16(v);
        }
      }
    }
  }
}

// ---------- combine (in-place over d_out): out[t] = w0*y[2t] + w1*y[2t+1] ----------
__global__ __launch_bounds__(256) void combine_kernel(
    const __hip_bfloat16* __restrict__ yb, const float* __restrict__ tokW,
    float* __restrict__ outp)
{
  const int t  = blockIdx.x;
  const int c0 = threadIdx.x * 8;
  const float w0 = tokW[t * 2], w1 = tokW[t * 2 + 1];
  const ushort4* p0 = reinterpret_cast<const ushort4*>(yb + (long)(2 * t) * HD + c0);
  const ushort4* p1 = reinterpret_cast<const ushort4*>(yb + (long)(2 * t + 1) * HD + c0);
  float4 o[2];
  #pragma unroll
  for (int h = 0; h < 2; h++){
    ushort4 a = p0[h], b = p1[h];
    o[h].x = w0 * bf2f(a.x) + w1 * bf2f(b.x);
    o[h].y = w0 * bf2f(a.y) + w1 * bf2f(b.y);
    o[h].z = w0 * bf2f(a.z) + w1 * bf2f(b.z);
    o[h].w = w0 * bf2f(a.w) + w1 * bf2f(b.w);
  }
  __syncthreads();   // all reads of this block's byte-range done before in-place overwrite
  float4* po = reinterpret_cast<float4*>(outp + (long)t * HD + c0);
  po[0] = o[0]; po[1] = o[1];
}

extern "C" void kernel_launch(void* const* d_in, const int* in_sizes, int n_in,
                              void* d_out, int out_size, void* d_ws, size_t ws_size,
                              hipStream_t stream)
{
  (void)in_sizes; (void)n_in; (void)out_size;
  const float* x     = (const float*)d_in[0];
  const float* gw    = (const float*)d_in[1];
  const float* wfc   = (const float*)d_in[2];
  const float* bfc   = (const float*)d_in[3];
  const float* wproj = (const float*)d_in[4];
  const float* bproj = (const float*)d_in[5];
  float* outp   = (float*)d_out;
  float* logits = outp + (size_t)NT * HD;
  __hip_bfloat16* yb = (__hip_bfloat16*)d_out;   // proj writes pair rows here; combine in-place

  char* ws = (char*)d_ws;
  size_t off = 0;
  auto alloc = [&](size_t b){ void* p = ws + off; off += (b + 255) & ~(size_t)255; return p; };

  // ---- slot-contiguous layout (preferred)
  const size_t XG_B  = (size_t)MAXSLOT * HD * 2;   // 75.5 MB
  const size_t HBS_B = (size_t)MAXSLOT * ID * 2;   // 151.0 MB
  const size_t WB_B  = (size_t)NE * ID * HD * 2;   // 134.2 MB
  const size_t MISC_B = (size_t)MAXSLOT*4 + NT*2*4 + NT*2*4 + 4096;
  const bool slotPath = (XG_B + HBS_B + WB_B + MISC_B + 4096) <= ws_size;

  __hip_bfloat16 *xg, *hb, *wB;
  if (slotPath){
    xg = (__hip_bfloat16*)alloc(XG_B);
    hb = (__hip_bfloat16*)alloc(HBS_B);
    wB = (__hip_bfloat16*)alloc(WB_B);
  } else {
    xg = (__hip_bfloat16*)alloc((size_t)NT * HD * 2);        // token-order xb
    hb = (__hip_bfloat16*)alloc((size_t)NT * 2 * ID * 2);    // pair-space hb
    wB = (__hip_bfloat16*)alloc(WB_B);
  }
  int*   slotTok = (int*)alloc(MAXSLOT * 4);
  int*   tokExp  = (int*)alloc(NT * 2 * 4);
  float* tokW    = (float*)alloc(NT * 2 * 4);
  int*   meta    = (int*)alloc(256);
  int* cnt = meta; int* cursor = meta + 8; int* padOff = meta + 16;

  hipMemsetAsync(meta, 0, 256, stream);
  hipMemsetAsync(slotTok, 0xFF, MAXSLOT * 4, stream);

  router_kernel<<<NT / 4, 256, 0, stream>>>(x, gw, logits, tokExp, tokW, cnt);
  offsets_kernel<<<1, 64, 0, stream>>>(cnt, padOff);
  scatter_kernel<<<NT / 256, 256, 0, stream>>>(tokExp, padOff, cursor, slotTok);

  if (slotPath){
    gather_cvt_kernel<<<MAXSLOT, 256, 0, stream>>>(x, slotTok, xg);
    cvt_kernel<<<2048, 256, 0, stream>>>(wfc, wB, NE * ID * HD / 4);
    moe_gemm8<0, 0, 0, ID, HD><<<(ID / 256) * MAXRB, 512, 0, stream>>>(xg, wB, bfc, slotTok, padOff, hb);
    cvt_kernel<<<2048, 256, 0, stream>>>(wproj, wB, NE * HD * ID / 4);
    moe_gemm8<0, 1, 1, HD, ID><<<(HD / 256) * MAXRB, 512, 0, stream>>>(hb, wB, bproj, slotTok, padOff, yb);
  } else {
    cvt_kernel<<<2048, 256, 0, stream>>>(x, xg, NT * HD / 4);
    cvt_kernel<<<2048, 256, 0, stream>>>(wfc, wB, NE * ID * HD / 4);
    moe_gemm8<1, 1, 0, ID, HD><<<(ID / 256) * MAXRB, 512, 0, stream>>>(xg, wB, bfc, slotTok, padOff, hb);
    cvt_kernel<<<2048, 256, 0, stream>>>(wproj, wB, NE * HD * ID / 4);
    moe_gemm8<2, 1, 1, HD, ID><<<(HD / 256) * MAXRB, 512, 0, stream>>>(hb, wB, bproj, slotTok, padOff, yb);
  }

  combine_kernel<<<NT, 256, 0, stream>>>(yb, tokW, outp);
}